// Round 2
// baseline (284.787 us; speedup 1.0000x reference)
//
#include <hip/hip_runtime.h>
#include <hip/hip_bf16.h>

// MHA: B=2 S=2048 DM=1024 H=16 DK=64.  All heavy math in bf16 MFMA, fp32 accum.
#define DM 1024
#define SL 2048
#define NH 16
#define DK 64

typedef __bf16 bf16;
typedef __bf16 bf16x8 __attribute__((ext_vector_type(8)));
typedef __bf16 bf16x4 __attribute__((ext_vector_type(4)));
typedef float f32x4 __attribute__((ext_vector_type(4)));
typedef float f32x16 __attribute__((ext_vector_type(16)));

__device__ __forceinline__ void gll16(const void* g, void* l) {
  __builtin_amdgcn_global_load_lds(
      (const __attribute__((address_space(1))) unsigned int*)g,
      (__attribute__((address_space(3))) unsigned int*)l, 16, 0, 0);
}

// ---------------- fp32 -> bf16 convert for q,k,v ----------------
__global__ __launch_bounds__(256) void cvt_x_kernel(
    const float* __restrict__ q, const float* __restrict__ k, const float* __restrict__ v,
    bf16* __restrict__ xq, bf16* __restrict__ xk, bf16* __restrict__ xv) {
  const float* src; bf16* dst;
  if (blockIdx.y == 0)      { src = q; dst = xq; }
  else if (blockIdx.y == 1) { src = k; dst = xk; }
  else                      { src = v; dst = xv; }
  int i = (blockIdx.x * 256 + threadIdx.x) * 8;
  f32x4 a = *(const f32x4*)(src + i);
  f32x4 b = *(const f32x4*)(src + i + 4);
  bf16x8 o;
  o[0]=(bf16)a[0]; o[1]=(bf16)a[1]; o[2]=(bf16)a[2]; o[3]=(bf16)a[3];
  o[4]=(bf16)b[0]; o[5]=(bf16)b[1]; o[6]=(bf16)b[2]; o[7]=(bf16)b[3];
  *(bf16x8*)(dst + i) = o;
}

// ------------- weight transpose + convert: T[n][k] = W[k][n] -------------
__global__ __launch_bounds__(256) void cvt_w_kernel(
    const float* __restrict__ W0, const float* __restrict__ W1,
    const float* __restrict__ W2, const float* __restrict__ W3,
    bf16* __restrict__ T0, bf16* __restrict__ T1,
    bf16* __restrict__ T2, bf16* __restrict__ T3) {
  const float* W; bf16* T;
  switch (blockIdx.y) {
    case 0:  W = W0; T = T0; break;
    case 1:  W = W1; T = T1; break;
    case 2:  W = W2; T = T2; break;
    default: W = W3; T = T3; break;
  }
  __shared__ float t[64][65];
  const int tid = threadIdx.x;
  const int tx = blockIdx.x & 15, ty = blockIdx.x >> 4;  // k-tile ty, n-tile tx
  const int cr = tid >> 4, cc = tid & 15;
  #pragma unroll
  for (int rr = 0; rr < 4; ++rr) {
    int row = rr*16 + cr;
    f32x4 val = *(const f32x4*)(W + (ty*64 + row)*DM + tx*64 + cc*4);
    t[row][cc*4+0] = val[0]; t[row][cc*4+1] = val[1];
    t[row][cc*4+2] = val[2]; t[row][cc*4+3] = val[3];
  }
  __syncthreads();
  #pragma unroll
  for (int rr = 0; rr < 4; ++rr) {
    int nrow = rr*16 + cr;
    bf16x4 o;
    o[0] = (bf16)t[cc*4+0][nrow]; o[1] = (bf16)t[cc*4+1][nrow];
    o[2] = (bf16)t[cc*4+2][nrow]; o[3] = (bf16)t[cc*4+3][nrow];
    *(bf16x4*)(T + (tx*64 + nrow)*DM + ty*64 + cc*4) = o;
  }
}

// ---------------- 128x128 tile GEMM, BK=64, global_load_lds + XOR swizzle ----------------
// C[m][n] = sum_k A[m][k] * Bt[n][k]  (+bias).  OUT_HEADS: write bf16 [B][H][S][DK]; else fp32 row-major.
template<int OUT_HEADS>
__device__ __forceinline__ void gemm_core(
    const bf16* __restrict__ A, const bf16* __restrict__ Bt, const float* __restrict__ bias,
    bf16* __restrict__ outH, float* __restrict__ outF) {
  const int mt = blockIdx.x >> 3, nt = blockIdx.x & 7;
  const int m0 = mt*128, n0 = nt*128;
  __shared__ __attribute__((aligned(16))) bf16 As[128*64];
  __shared__ __attribute__((aligned(16))) bf16 Bs[128*64];
  const int tid = threadIdx.x, lane = tid & 63, w = tid >> 6;
  const int wm = w >> 1, wn = w & 1;
  f32x4 acc[4][4];
  #pragma unroll
  for (int x = 0; x < 4; ++x)
    #pragma unroll
    for (int y = 0; y < 4; ++y)
      #pragma unroll
      for (int e = 0; e < 4; ++e) acc[x][y][e] = 0.f;

  for (int kt = 0; kt < 16; ++kt) {
    const int k0 = kt*64;
    __syncthreads();
    #pragma unroll
    for (int i = 0; i < 4; ++i) {
      int idx = (i*4 + w)*64 + lane;     // 16B-slot index in [0,1024)
      int r = idx >> 3;                  // row 0..127
      int s = (idx & 7) ^ (r & 7);       // logical slot for this physical slot (involution)
      gll16(A  + (m0 + r)*DM + k0 + s*8, &As[(i*4 + w)*512]);
      gll16(Bt + (n0 + r)*DM + k0 + s*8, &Bs[(i*4 + w)*512]);
    }
    __syncthreads();
    bf16x8 bfr[4][2];
    #pragma unroll
    for (int ni = 0; ni < 4; ++ni) {
      int row = wn*64 + ni*16 + (lane & 15);
      #pragma unroll
      for (int c = 0; c < 2; ++c) {
        int slot = (lane >> 4) + c*4;
        bfr[ni][c] = *(const bf16x8*)&Bs[row*64 + ((slot ^ (row & 7)) << 3)];
      }
    }
    #pragma unroll
    for (int mi = 0; mi < 4; ++mi) {
      int row = wm*64 + mi*16 + (lane & 15);
      bf16x8 a0 = *(const bf16x8*)&As[row*64 + ((((lane >> 4)    ) ^ (row & 7)) << 3)];
      bf16x8 a1 = *(const bf16x8*)&As[row*64 + ((((lane >> 4) + 4) ^ (row & 7)) << 3)];
      #pragma unroll
      for (int ni = 0; ni < 4; ++ni) {
        acc[mi][ni] = __builtin_amdgcn_mfma_f32_16x16x32_bf16(a0, bfr[ni][0], acc[mi][ni], 0, 0, 0);
        acc[mi][ni] = __builtin_amdgcn_mfma_f32_16x16x32_bf16(a1, bfr[ni][1], acc[mi][ni], 0, 0, 0);
      }
    }
  }
  #pragma unroll
  for (int ni = 0; ni < 4; ++ni) {
    int n = n0 + wn*64 + ni*16 + (lane & 15);
    float bv = bias[n];
    #pragma unroll
    for (int mi = 0; mi < 4; ++mi) {
      #pragma unroll
      for (int j = 0; j < 4; ++j) {
        int m = m0 + wm*64 + mi*16 + ((lane >> 4) << 2) + j;
        float val = acc[mi][ni][j] + bv;
        if (OUT_HEADS) {
          int bb = m >> 11, ss = m & 2047, hh = n >> 6, dd = n & 63;
          outH[(((bb << 4) + hh)*SL + ss)*DK + dd] = (bf16)val;
        } else {
          outF[m*DM + n] = val;
        }
      }
    }
  }
}

__global__ __launch_bounds__(256, 2) void proj_gemm_kernel(
    const bf16* XQ, const bf16* XK, const bf16* XV,
    const bf16* WTQp, const bf16* WTKp, const bf16* WTVp,
    const float* bq, const float* bk, const float* bv,
    bf16* QHp, bf16* KHp, bf16* VHp) {
  const bf16 *A, *Bt; const float* bias; bf16* O;
  if (blockIdx.y == 0)      { A = XQ; Bt = WTQp; bias = bq; O = QHp; }
  else if (blockIdx.y == 1) { A = XK; Bt = WTKp; bias = bk; O = KHp; }
  else                      { A = XV; Bt = WTVp; bias = bv; O = VHp; }
  gemm_core<1>(A, Bt, bias, O, nullptr);
}

__global__ __launch_bounds__(256, 2) void out_gemm_kernel(
    const bf16* CTXp, const bf16* WTOp, const float* bo, float* out) {
  gemm_core<0>(CTXp, WTOp, bo, nullptr, out);
}

// ---------------- flash attention, swapped-QK^T, 32x32x16 MFMA ----------------
// 4 waves x 32-query strips (QBLK=128), KBLK=64, key mask as additive -1e9.
__global__ __launch_bounds__(256, 2) void attn_kernel(
    const bf16* __restrict__ QHp, const bf16* __restrict__ KHp,
    const bf16* __restrict__ VHp, const int* __restrict__ msk,
    bf16* __restrict__ CTXp) {
  const int bh = blockIdx.y, b = bh >> 4, h = bh & 15;
  const int q0 = blockIdx.x * 128;
  const bf16* Qp = QHp + bh * SL * DK;
  const bf16* Kp = KHp + bh * SL * DK;
  const bf16* Vp = VHp + bh * SL * DK;
  const int* mp = msk + b * SL;
  __shared__ __attribute__((aligned(16))) bf16 Ks[64*64];     // [key][d] swizzled
  __shared__ __attribute__((aligned(16))) bf16 Vts[64*64];    // [d][key] swizzled
  __shared__ __attribute__((aligned(16))) bf16 Ps[4][32*64];  // per-wave [q][key] swizzled
  __shared__ __attribute__((aligned(16))) float mAdd[64];
  const int tid = threadIdx.x, lane = tid & 63, w = tid >> 6;
  const int hi = lane >> 5, l5 = lane & 31;
  const float L2E = 1.44269504f;

  // Q fragments (held in regs whole kernel): B-operand col = local q = l5
  bf16x8 qf[4];
  {
    const bf16* qr = Qp + (q0 + w*32 + l5)*DK + hi*8;
    #pragma unroll
    for (int c = 0; c < 4; ++c) qf[c] = *(const bf16x8*)(qr + c*16);
  }
  f32x16 o0, o1;
  #pragma unroll
  for (int e = 0; e < 16; ++e) { o0[e] = 0.f; o1[e] = 0.f; }
  float m_run = -1e30f, l_run = 0.f;

  for (int kt = 0; kt < 32; ++kt) {
    const int k0 = kt*64;
    __syncthreads();
    // stage K [64][64] via global_load_lds, source pre-swizzled
    #pragma unroll
    for (int i = 0; i < 2; ++i) {
      int idx = (i*4 + w)*64 + lane;
      int r = idx >> 3;
      int s = (idx & 7) ^ (r & 7);
      gll16(Kp + (k0 + r)*DK + s*8, &Ks[(i*4 + w)*512]);
    }
    // stage V transposed: Vts[d][key], swizzled
    #pragma unroll
    for (int i = 0; i < 2; ++i) {
      int idx = i*256 + tid;
      int key = idx >> 3, dc = idx & 7;
      bf16x8 vv = *(const bf16x8*)(Vp + (k0 + key)*DK + dc*8);
      #pragma unroll
      for (int j = 0; j < 8; ++j) {
        int d = dc*8 + j;
        Vts[d*64 + ((((key >> 3)) ^ (d & 7)) << 3) + (key & 7)] = vv[j];
      }
    }
    if (tid < 64) mAdd[tid] = (mp[k0 + tid] == 0) ? -1.0e9f : 0.0f;
    __syncthreads();

    // ST[key][q] = K @ Q^T  (swapped => softmax reduce is reg-local + 1 shuffle)
    f32x16 s0, s1;
    #pragma unroll
    for (int e = 0; e < 16; ++e) { s0[e] = 0.f; s1[e] = 0.f; }
    #pragma unroll
    for (int c = 0; c < 4; ++c) {
      int sl = 2*c + hi;
      int r0 = l5, r1 = 32 + l5;
      bf16x8 kf0 = *(const bf16x8*)&Ks[r0*64 + ((sl ^ (r0 & 7)) << 3)];
      bf16x8 kf1 = *(const bf16x8*)&Ks[r1*64 + ((sl ^ (r1 & 7)) << 3)];
      s0 = __builtin_amdgcn_mfma_f32_32x32x16_bf16(kf0, qf[c], s0, 0, 0, 0);
      s1 = __builtin_amdgcn_mfma_f32_32x32x16_bf16(kf1, qf[c], s1, 0, 0, 0);
    }
    // scale + mask + online softmax (column q = l5; rows = keys)
    float pv_[32];
    float mt = -1e30f;
    #pragma unroll
    for (int half = 0; half < 2; ++half) {
      #pragma unroll
      for (int qd = 0; qd < 4; ++qd) {
        f32x4 ma = *(const f32x4*)&mAdd[half*32 + qd*8 + hi*4];
        #pragma unroll
        for (int j = 0; j < 4; ++j) {
          float val = (half ? s1[qd*4+j] : s0[qd*4+j]) * 0.125f + ma[j];
          pv_[half*16 + qd*4 + j] = val;
          mt = fmaxf(mt, val);
        }
      }
    }
    mt = fmaxf(mt, __shfl_xor(mt, 32));
    float mnew = fmaxf(m_run, mt);
    float sf = exp2f((m_run - mnew) * L2E);
    m_run = mnew;
    float lsum = 0.f;
    #pragma unroll
    for (int t = 0; t < 32; ++t) {
      float p = exp2f((pv_[t] - mnew) * L2E);
      pv_[t] = p; lsum += p;
    }
    lsum += __shfl_xor(lsum, 32);
    l_run = l_run * sf + lsum;
    // rescale O (rows are q = crow(reg,hi); sf lives at lane == q)
    #pragma unroll
    for (int reg = 0; reg < 16; ++reg) {
      int crow = (reg & 3) + ((reg >> 2) << 3) + (hi << 2);
      float s_ = __shfl(sf, crow);
      o0[reg] *= s_; o1[reg] *= s_;
    }
    // store P (bf16) to per-wave swizzled LDS: Ps[q][key]
    #pragma unroll
    for (int half = 0; half < 2; ++half) {
      #pragma unroll
      for (int qd = 0; qd < 4; ++qd) {
        #pragma unroll
        for (int pr = 0; pr < 2; ++pr) {
          int key = half*32 + qd*8 + hi*4 + pr*2;
          unsigned short ulo = __builtin_bit_cast(unsigned short, (bf16)pv_[half*16 + qd*4 + pr*2]);
          unsigned short uhi = __builtin_bit_cast(unsigned short, (bf16)pv_[half*16 + qd*4 + pr*2 + 1]);
          unsigned pk = (unsigned)ulo | ((unsigned)uhi << 16);
          *(unsigned*)&Ps[w][l5*64 + (((key >> 3) ^ (l5 & 7)) << 3) + (key & 7)] = pk;
        }
      }
    }
    // PV: O[q][d] += P[q][k] * V[k][d]
    #pragma unroll
    for (int c = 0; c < 4; ++c) {
      int sl = 2*c + hi;
      bf16x8 pa  = *(const bf16x8*)&Ps[w][l5*64 + ((sl ^ (l5 & 7)) << 3)];
      int r0 = l5, r1 = 32 + l5;
      bf16x8 vf0 = *(const bf16x8*)&Vts[r0*64 + ((sl ^ (r0 & 7)) << 3)];
      bf16x8 vf1 = *(const bf16x8*)&Vts[r1*64 + ((sl ^ (r1 & 7)) << 3)];
      o0 = __builtin_amdgcn_mfma_f32_32x32x16_bf16(pa, vf0, o0, 0, 0, 0);
      o1 = __builtin_amdgcn_mfma_f32_32x32x16_bf16(pa, vf1, o1, 0, 0, 0);
    }
  }
  // epilogue: divide by l, write ctx[b][s][h*64+d] bf16
  float inv = 1.f / l_run;
  const int sbase = (b * SL) * DM + h * DK;
  #pragma unroll
  for (int reg = 0; reg < 16; ++reg) {
    int crow = (reg & 3) + ((reg >> 2) << 3) + (hi << 2);
    float iv = __shfl(inv, crow);
    int srow = q0 + w*32 + crow;
    CTXp[sbase + srow*DM + l5]      = (bf16)(o0[reg] * iv);
    CTXp[sbase + srow*DM + 32 + l5] = (bf16)(o1[reg] * iv);
  }
}

extern "C" void kernel_launch(void* const* d_in, const int* in_sizes, int n_in,
                              void* d_out, int out_size, void* d_ws, size_t ws_size,
                              hipStream_t stream) {
  const float* q  = (const float*)d_in[0];
  const float* k  = (const float*)d_in[1];
  const float* v  = (const float*)d_in[2];
  const int*  msk = (const int*)d_in[3];
  const float* Wq = (const float*)d_in[4];
  const float* bq = (const float*)d_in[5];
  const float* Wk = (const float*)d_in[6];
  const float* bk = (const float*)d_in[7];
  const float* Wv = (const float*)d_in[8];
  const float* bv = (const float*)d_in[9];
  const float* Wo = (const float*)d_in[10];
  const float* bo = (const float*)d_in[11];
  char* ws = (char*)d_ws;
  bf16* XQ  = (bf16*)(ws + 0);
  bf16* XK  = (bf16*)(ws + 8388608);
  bf16* XV  = (bf16*)(ws + 16777216);
  bf16* WTQ = (bf16*)(ws + 25165824);
  bf16* WTK = (bf16*)(ws + 27262976);
  bf16* WTV = (bf16*)(ws + 29360128);
  bf16* WTO = (bf16*)(ws + 31457280);
  bf16* QHb = (bf16*)(ws + 33554432);
  bf16* KHb = (bf16*)(ws + 41943040);
  bf16* VHb = (bf16*)(ws + 50331648);
  bf16* CTX = (bf16*)(ws + 58720256);   // total 64 MiB
  float* out = (float*)d_out;

  cvt_x_kernel<<<dim3(2048, 3), 256, 0, stream>>>(q, k, v, XQ, XK, XV);
  cvt_w_kernel<<<dim3(256, 4), 256, 0, stream>>>(Wq, Wk, Wv, Wo, WTQ, WTK, WTV, WTO);
  proj_gemm_kernel<<<dim3(256, 3), 256, 0, stream>>>(XQ, XK, XV, WTQ, WTK, WTV,
                                                     bq, bk, bv, QHb, KHb, VHb);
  attn_kernel<<<dim3(16, 32), 256, 0, stream>>>(QHb, KHb, VHb, msk, CTX);
  out_gemm_kernel<<<dim3(256, 1), 256, 0, stream>>>(CTX, WTO, bo, out);
}